// Round 7
// baseline (1404.826 us; speedup 1.0000x reference)
//
#include <hip/hip_runtime.h>
#include <stdint.h>

#define BB 64
#define TT 2048
#define KK 128
#define HF 64
#define CH 32          // bi-staging chunk: steps per chunk
#define WSTR 260       // words per lane W-region: base%32 = 4k -> rotated quads

typedef float f32x16 __attribute__((ext_vector_type(16)));
typedef float f32x2  __attribute__((ext_vector_type(2)));

__device__ __forceinline__ float waveMax(float v) {
#pragma unroll
    for (int off = 32; off; off >>= 1) v = fmaxf(v, __shfl_xor(v, off, 64));
    return v;
}
__device__ __forceinline__ float waveSum(float v) {
#pragma unroll
    for (int off = 32; off; off >>= 1) v += __shfl_xor(v, off, 64);
    return v;
}
__device__ __forceinline__ int waveSumI(int v) {
#pragma unroll
    for (int off = 32; off; off >>= 1) v += __shfl_xor(v, off, 64);
    return v;
}
__device__ __forceinline__ float waveMaxFast(float v) {
    int x = __builtin_amdgcn_mov_dpp(__float_as_int(v), 0xB1, 0xf, 0xf, true);
    v = fmaxf(v, __int_as_float(x));
    x = __builtin_amdgcn_mov_dpp(__float_as_int(v), 0x4E, 0xf, 0xf, true);
    v = fmaxf(v, __int_as_float(x));
#pragma unroll
    for (int off = 4; off <= 32; off <<= 1) v = fmaxf(v, __shfl_xor(v, off, 64));
    return v;
}

// intra-wave LDS ordering (no barrier: single wave per block)
__device__ __forceinline__ void wave_lds_fence() {
    asm volatile("s_waitcnt lgkmcnt(0)" ::: "memory");
}
// legacy 2-wave barrier (fallback kernel only)
__device__ __forceinline__ void lds_barrier() {
    asm volatile("s_waitcnt lgkmcnt(0)\n\ts_barrier" ::: "memory");
}

#define PKFMA(ep, wp, acc) acc = __builtin_elementwise_fma(ep, wp, acc)

#define MATVEC_QUARTER(Wa, Wb, ev, sOut) {                          \
    const float4 e0 = ev[0], e1 = ev[1], e2 = ev[2], e3 = ev[3];    \
    const float4 e4 = ev[4], e5 = ev[5], e6 = ev[6], e7 = ev[7];    \
    f32x2 a0 = {0.f,0.f}, a1 = {0.f,0.f}, a2 = {0.f,0.f}, a3 = {0.f,0.f}; \
    PKFMA(((f32x2){e0.x, e0.y}), ((f32x2){Wa[0],  Wa[1]}),  a0);    \
    PKFMA(((f32x2){e0.z, e0.w}), ((f32x2){Wa[2],  Wa[3]}),  a1);    \
    PKFMA(((f32x2){e1.x, e1.y}), ((f32x2){Wa[4],  Wa[5]}),  a2);    \
    PKFMA(((f32x2){e1.z, e1.w}), ((f32x2){Wa[6],  Wa[7]}),  a3);    \
    PKFMA(((f32x2){e2.x, e2.y}), ((f32x2){Wa[8],  Wa[9]}),  a0);    \
    PKFMA(((f32x2){e2.z, e2.w}), ((f32x2){Wa[10], Wa[11]}), a1);    \
    PKFMA(((f32x2){e3.x, e3.y}), ((f32x2){Wa[12], Wa[13]}), a2);    \
    PKFMA(((f32x2){e3.z, e3.w}), ((f32x2){Wa[14], Wa[15]}), a3);    \
    PKFMA(((f32x2){e4.x, e4.y}), ((f32x2){Wb[0],  Wb[1]}),  a0);    \
    PKFMA(((f32x2){e4.z, e4.w}), ((f32x2){Wb[2],  Wb[3]}),  a1);    \
    PKFMA(((f32x2){e5.x, e5.y}), ((f32x2){Wb[4],  Wb[5]}),  a2);    \
    PKFMA(((f32x2){e5.z, e5.w}), ((f32x2){Wb[6],  Wb[7]}),  a3);    \
    PKFMA(((f32x2){e6.x, e6.y}), ((f32x2){Wb[8],  Wb[9]}),  a0);    \
    PKFMA(((f32x2){e6.z, e6.w}), ((f32x2){Wb[10], Wb[11]}), a1);    \
    PKFMA(((f32x2){e7.x, e7.y}), ((f32x2){Wb[12], Wb[13]}), a2);    \
    PKFMA(((f32x2){e7.z, e7.w}), ((f32x2){Wb[14], Wb[15]}), a3);    \
    const f32x2 s2 = (a0 + a1) + (a2 + a3);                         \
    sOut = s2[0] + s2[1]; }

// SINGLE-WAVE forward/backward kernel (R6 post-mortem: 2-wave step was
// DS-pipe + barrier-sync bound at ~2000 cyc). One wave of 64 lanes; lane k
// owns output states (k, k+64). ZERO barriers; renorm `r` lives in registers
// (DPP wave-max only). W in LDS as per-lane pair streams:
//   region lane k at word k*260 (260%32==4 -> quad rotation);
//   WP0 pair j at words [2j,2j+1] = (W[k][j], W[k][j+64]);
//   WP1 at +128 words, same for output k+64.
// e as 64 pairs (e[j], e[j+64]) -> lane writes its pair b64, reads 32
// uniform-broadcast b128. bi staged in composed 32-step chunks (R6, proven).
extern "C" __global__ __launch_bounds__(64, 1)
void crf_fb_kernel(const float* __restrict__ em,
                   const int* __restrict__ mask,
                   const int* __restrict__ tgt,
                   const float* __restrict__ trans,
                   const float* __restrict__ start,
                   const int* __restrict__ forb,
                   float* __restrict__ ef,      // [128][KK] forward exp-alpha
                   float* __restrict__ db,      // [128][KK] backward exp-beta
                   float* __restrict__ Mfb)     // [256] scales: fwd 0..127, bwd 128..255
{
    const int k    = threadIdx.x;       // lane 0..63; owns states k, k+64
    const bool fwdDir = (blockIdx.x < 2 * BB);
    const int c    = blockIdx.x & (2 * BB - 1);
    const int b    = c & (BB - 1);
    const bool sup = (c < BB);

    extern __shared__ __align__(16) float Wlds[];    // 64*260 words = 66,560 B
    __shared__ __align__(16) float biLDS[2][CH][KK]; // 32 KB composed bi chunks
    __shared__ __align__(16) float eLDS[2][2 * HF];  // 64 pairs (e[j], e[j+64])

    // ---- length: one wave covers 2048 mask ints (8 int4 per lane) ----
    int ps = 0;
    const int4* __restrict__ mrow = (const int4*)(mask + (size_t)b * TT);
#pragma unroll
    for (int it = 0; it < 8; ++it) {
        const int4 m4 = mrow[k + HF * it];
        ps += m4.x + m4.y + m4.z + m4.w;
    }
    const int len = waveSumI(ps);        // all lanes hold total

    const float* __restrict__ emrow = em + (size_t)b * TT * KK;
    const int* __restrict__ trow = tgt + (size_t)b * TT * KK;
    const int col2 = k << 1;             // staging columns (col2, col2+1)

    // ---- W into LDS (cooperative, coalesced global reads) ----
    // value exp(trans[r][c]):  fwd -> W[out=c][in=r];  bwd -> W[out=r][in=c]
    // addr(out,in) = (out&63)*WSTR + ((out>>6)<<7) + ((in&63)<<1) + (in>>6)
    {
#pragma unroll 4
        for (int r = 0; r < KK; ++r) {
            const float2 tv = *(const float2*)(trans + r * KK + col2);
            const int2   fv = *(const int2*)  (forb  + r * KK + col2);
            const float w0 = fv.x ? 0.0f : __expf(tv.x);
            const float w1 = fv.y ? 0.0f : __expf(tv.y);
            const int o0 = fwdDir ? col2     : r;
            const int i0 = fwdDir ? r        : col2;
            const int o1 = fwdDir ? col2 + 1 : r;
            const int i1 = fwdDir ? r        : col2 + 1;
            Wlds[(o0 & 63) * WSTR + ((o0 >> 6) << 7) + ((i0 & 63) << 1) + (i0 >> 6)] = w0;
            Wlds[(o1 & 63) * WSTR + ((o1 >> 6) << 7) + ((i1 & 63) << 1) + (i1 >> 6)] = w1;
        }
    }

    const int mid = len >> 1;
    const int N   = fwdDir ? mid : (len - 1 - mid);   // serial steps (>=511)
    const int t0  = fwdDir ? 0 : (len - 1);

    // ---- init vector at t0: exact max renorm (registers only) ----
    float v0x = emrow[(size_t)t0 * KK + k];
    float v0y = emrow[(size_t)t0 * KK + k + HF];
    if (sup) {
        if (!trow[(size_t)t0 * KK + k])      v0x = -100000.0f;
        if (!trow[(size_t)t0 * KK + k + HF]) v0y = -100000.0f;
    }
    v0x += start[k]; v0y += start[k + HF];
    const float M0 = waveMax(fmaxf(v0x, v0y));
    double M = (double)M0;
    f32x2 eNew = { __expf(v0x - M0), __expf(v0y - M0) };
    *(f32x2*)&eLDS[0][col2] = eNew;      // pair k

    // ---- chunked composed-bi staging (proven R6 structure, 1-wave) ----
    const float2 stc = *(const float2*)(start + col2);
    auto stageChunk = [&](int bf, int m) {
        const int base_n = 1 + CH * m;
        const int t_base = fwdDir ? base_n : (len - base_n - CH);
#pragma unroll
        for (int row = 0; row < CH; ++row) {
            const int t = t_base + row;
            float2 e2 = *(const float2*)(emrow + (size_t)t * KK + col2);
            if (sup) {
                const int2 t2 = *(const int2*)(trow + (size_t)t * KK + col2);
                e2.x = t2.x ? e2.x : -100000.0f;
                e2.y = t2.y ? e2.y : -100000.0f;
            }
            e2.x += stc.x; e2.y += stc.y;
            *(float2*)&biLDS[bf][row][col2] = e2;
        }
    };

    const int nChunks = (N + CH - 1) / CH;
    int buf = 0;
    stageChunk(0, 0);
    const float4* __restrict__ wp = (const float4*)(Wlds + k * WSTR); // wp[c], wp[32+c]
    float rPend = 0.0f;
    wave_lds_fence();                    // eLDS[0] + biLDS[0] + Wlds visible

    for (int m = 0; m < nChunks; ++m) {
        if (m + 1 < nChunks) stageChunk(buf ^ 1, m + 1);
        const int base_n = 1 + CH * m;
        const int rem = N - base_n + 1;
        const int lim = rem < CH ? rem : CH;
#pragma unroll 4
        for (int i = 0; i < lim; ++i) {
            const int n = base_n + i;
            const int p = (n - 1) & 1;
            const int pos = fwdDir ? i : (CH - 1 - i);

            float bx = biLDS[buf][pos][k];
            float by = biLDS[buf][pos][k + HF];
            if (!fwdDir && n == N) { bx = 0.0f; by = 0.0f; } // fwd owns bi_mid

            // renorm cadence (proven): measure at n%4==3 from prev eNew,
            // apply at n%4==0. All in registers -- no LDS, no barrier.
            if ((n & 3) == 3) {
                rPend = waveMaxFast(__logf(fmaxf(eNew[0], eNew[1])));
            }
            float r = 0.0f;
            if ((n & 3) == 0) { r = rPend; M += (double)r; }
            const float fx = __expf(bx - r);   // overlaps matvec
            const float fy = __expf(by - r);

            // matvec: 32 e-broadcast b128 + 64 per-lane W b128, 128 pk_fma
            const float4* __restrict__ ev = (const float4*)eLDS[p];
            f32x2 a0 = {0.f,0.f}, a0b = {0.f,0.f};
            f32x2 a1 = {0.f,0.f}, a1b = {0.f,0.f};
#pragma unroll 8
            for (int cc = 0; cc < 32; ++cc) {
                const float4 E  = ev[cc];          // pairs 2cc, 2cc+1 (uniform)
                const float4 W0 = wp[cc];          // out k  : pairs 2cc, 2cc+1
                const float4 W1 = wp[32 + cc];     // out k+64
                PKFMA(((f32x2){E.x, E.y}), ((f32x2){W0.x, W0.y}), a0);
                PKFMA(((f32x2){E.z, E.w}), ((f32x2){W0.z, W0.w}), a0b);
                PKFMA(((f32x2){E.x, E.y}), ((f32x2){W1.x, W1.y}), a1);
                PKFMA(((f32x2){E.z, E.w}), ((f32x2){W1.z, W1.w}), a1b);
            }
            const f32x2 s0v = a0 + a0b;
            const f32x2 s1v = a1 + a1b;
            eNew[0] = (s0v[0] + s0v[1]) * fx;
            eNew[1] = (s1v[0] + s1v[1]) * fy;
            *(f32x2*)&eLDS[p ^ 1][col2] = eNew;

            wave_lds_fence();            // order write -> next-step reads
        }
        buf ^= 1;
    }

    float* __restrict__ dst = (fwdDir ? ef : db) + (size_t)c * KK;
    dst[k]      = eNew[0];
    dst[k + HF] = eNew[1];
    if (k == 0) Mfb[(fwdDir ? 0 : 2 * BB) + c] = (float)M;
}

// z[c] = Mf[c] + Mb[c] + log(dot(ef[c], db[c])); out[b] = z[b] - z[b+64]
extern "C" __global__ void crf_combine_kernel(const float* __restrict__ ef,
                                              const float* __restrict__ db,
                                              const float* __restrict__ Mfb,
                                              float* __restrict__ out)
{
    const int b = blockIdx.x;
    const int tid = threadIdx.x;         // 0..127 = state
    const int wv = tid >> 6, lane = tid & 63;
    __shared__ float red[2][2];
    __shared__ float z[2];
#pragma unroll
    for (int s = 0; s < 2; ++s) {
        const int c = b + s * BB;
        const float v = ef[(size_t)c * KK + tid] * db[(size_t)c * KK + tid];
        const float p = waveSum(v);
        if (lane == 0) red[s][wv] = p;
    }
    __syncthreads();
    if (tid < 2) {
        const int c = b + tid * BB;
        z[tid] = Mfb[c] + Mfb[2 * BB + c] + __logf(red[tid][0] + red[tid][1]);
    }
    __syncthreads();
    if (tid == 0) out[b] = z[0] - z[1];
}

// ---------------- fallback (proven): used only if ws is too small ----------
__device__ __forceinline__ float waveMaxFastFB(float v) {
    int x = __builtin_amdgcn_mov_dpp(__float_as_int(v), 0xB1, 0xf, 0xf, true);
    v = fmaxf(v, __int_as_float(x));
    x = __builtin_amdgcn_mov_dpp(__float_as_int(v), 0x4E, 0xf, 0xf, true);
    v = fmaxf(v, __int_as_float(x));
#pragma unroll
    for (int off = 4; off <= 32; off <<= 1) v = fmaxf(v, __shfl_xor(v, off, 64));
    return v;
}
__device__ __forceinline__ float quadSum(float s) {
    int x = __builtin_amdgcn_mov_dpp(__float_as_int(s), 0xB1, 0xf, 0xf, true);
    s += __int_as_float(x);
    x = __builtin_amdgcn_mov_dpp(__float_as_int(s), 0x4E, 0xf, 0xf, true);
    s += __int_as_float(x);
    return s;
}
extern "C" __global__ __launch_bounds__(512)
__attribute__((amdgpu_waves_per_eu(2, 2)))
void crf_chain_kernel(const float* __restrict__ em, const int* __restrict__ mask,
                      const int* __restrict__ tgt, const float* __restrict__ trans,
                      const float* __restrict__ start, const int* __restrict__ forb,
                      float* __restrict__ zbuf)
{
    const int tid = threadIdx.x;
    const int k = tid >> 2, q = tid & 3, w = tid >> 6, lane = tid & 63;
    const int c = blockIdx.x, b = c & (BB - 1);
    const bool sup = (c < BB);
    __shared__ __align__(16) float eLDS[2][KK];
    __shared__ float wmLDS[8];
    __shared__ float redLDS[8];
    __shared__ int lenLDS;
    if (tid == 0) lenLDS = 0;
    const int4 m4 = ((const int4*)(mask + (size_t)b * TT))[tid];
    int ps = m4.x + m4.y + m4.z + m4.w;
    ps = waveSumI(ps);
    __syncthreads();
    if (lane == 0) atomicAdd(&lenLDS, ps);
    const float st = start[k];
    const float* __restrict__ emrow = em + (size_t)b * TT * KK;
    const int* __restrict__ trow = tgt + (size_t)b * TT * KK;
    const int ib = q * 32;
    f32x16 Wa, Wb;
#pragma unroll
    for (int j = 0; j < 16; ++j) {
        Wa[j] = forb[(ib + j     ) * KK + k] ? 0.0f : __expf(trans[(ib + j     ) * KK + k]);
        Wb[j] = forb[(ib + 16 + j) * KK + k] ? 0.0f : __expf(trans[(ib + 16 + j) * KK + k]);
    }
    float v0 = emrow[k];
    if (sup && !trow[k]) v0 = -100000.0f;
    v0 += st;
    float wm0 = v0;
#pragma unroll
    for (int off = 32; off; off >>= 1) wm0 = fmaxf(wm0, __shfl_xor(wm0, off, 64));
    if (lane == 0) redLDS[w] = wm0;
    __syncthreads();
    const int len = lenLDS;
    float M0 = fmaxf(fmaxf(fmaxf(redLDS[0], redLDS[1]), fmaxf(redLDS[2], redLDS[3])),
                     fmaxf(fmaxf(redLDS[4], redLDS[5]), fmaxf(redLDS[6], redLDS[7])));
    double M = (double)M0;
    float eNew = __expf(v0 - M0);
    if (q == 0) eLDS[0][k] = eNew;
    auto bival = [&](int t) -> float {
        float e0 = emrow[(size_t)t * KK + k];
        if (sup) { if (!trow[(size_t)t * KK + k]) e0 = -100000.0f; }
        return e0 + st;
    };
    float biA = (len > 1) ? bival(1) : 0.0f;
    float biB = (len > 2) ? bival(2) : 0.0f;
    float biC = (len > 3) ? bival(3) : 0.0f;
    float biD = (len > 4) ? bival(4) : 0.0f;
    float sPrev = 1.0f, baPrev = 0.0f;
    lds_barrier();
#pragma unroll 4
    for (int t = 1; t < len; ++t) {
        const int p = (t - 1) & 1;
        const float biN = (t + 4 < len) ? bival(t + 4) : 0.0f;
        if ((t & 3) == 3) {
            const float u = __logf(sPrev) + baPrev;
            const float wmx = waveMaxFastFB(u);
            if (lane == 0) wmLDS[w] = wmx;
        }
        float r = 0.0f;
        if ((t & 3) == 0) {
            r = fmaxf(fmaxf(fmaxf(wmLDS[0], wmLDS[1]), fmaxf(wmLDS[2], wmLDS[3])),
                      fmaxf(fmaxf(wmLDS[4], wmLDS[5]), fmaxf(wmLDS[6], wmLDS[7])));
            M += (double)r;
        }
        const float ba = biA - r;
        const float f = __expf(ba);
        const float4* __restrict__ ev = (const float4*)eLDS[p] + q * 8;
        float s;
        MATVEC_QUARTER(Wa, Wb, ev, s)
        s = quadSum(s);
        eNew = s * f;
        if (q == 0) eLDS[p ^ 1][k] = eNew;
        sPrev = s; baPrev = ba;
        biA = biB; biB = biC; biC = biD; biD = biN;
        lds_barrier();
    }
    const float sm = waveSum((q == 0) ? eNew : 0.0f);
    if (lane == 0) redLDS[w] = sm;
    __syncthreads();
    if (tid == 0) {
        const float ss = ((redLDS[0] + redLDS[1]) + (redLDS[2] + redLDS[3]))
                       + ((redLDS[4] + redLDS[5]) + (redLDS[6] + redLDS[7]));
        zbuf[c] = (float)(M + (double)__logf(ss));
    }
}

extern "C" __global__ void crf_final_kernel(const float* __restrict__ z,
                                            float* __restrict__ out)
{
    const int b = threadIdx.x;
    out[b] = z[b] - z[b + BB];
}

extern "C" void kernel_launch(void* const* d_in, const int* in_sizes, int n_in,
                              void* d_out, int out_size, void* d_ws, size_t ws_size,
                              hipStream_t stream) {
    const float* em    = (const float*)d_in[0];
    const int*   mask  = (const int*)d_in[1];
    const int*   tgt   = (const int*)d_in[2];
    const float* trans = (const float*)d_in[3];
    const float* start = (const float*)d_in[4];
    const int*   forb  = (const int*)d_in[5];

    const size_t need = (size_t)(2 * 2 * BB * KK + 4 * BB) * sizeof(float); // 132 KB
    if (ws_size >= need) {
        float* ef  = (float*)d_ws;                       // [128][128]
        float* db  = ef + 2 * BB * KK;                   // [128][128]
        float* Mfb = db + 2 * BB * KK;                   // [256]
        const size_t wbytes = (size_t)HF * WSTR * sizeof(float); // 66,560 B
        crf_fb_kernel<<<4 * BB, 64, wbytes, stream>>>(em, mask, tgt, trans, start,
                                                      forb, ef, db, Mfb);
        crf_combine_kernel<<<BB, 128, 0, stream>>>(ef, db, Mfb, (float*)d_out);
    } else {
        float* zbuf = (float*)d_ws;
        crf_chain_kernel<<<2 * BB, 512, 0, stream>>>(em, mask, tgt, trans, start,
                                                     forb, zbuf);
        crf_final_kernel<<<1, BB, 0, stream>>>(zbuf, (float*)d_out);
    }
}

// Round 8
// 831.043 us; speedup vs baseline: 1.6904x; 1.6904x over previous
//
#include <hip/hip_runtime.h>
#include <stdint.h>

#define BB 64
#define TT 2048
#define KK 128
#define CH 32         // bi-staging chunk: steps per chunk

typedef float f32x16 __attribute__((ext_vector_type(16)));
typedef float f32x2  __attribute__((ext_vector_type(2)));

__device__ __forceinline__ float waveMax(float v) {
#pragma unroll
    for (int off = 32; off; off >>= 1) v = fmaxf(v, __shfl_xor(v, off, 64));
    return v;
}
__device__ __forceinline__ float waveSum(float v) {
#pragma unroll
    for (int off = 32; off; off >>= 1) v += __shfl_xor(v, off, 64);
    return v;
}
__device__ __forceinline__ int waveSumI(int v) {
#pragma unroll
    for (int off = 32; off; off >>= 1) v += __shfl_xor(v, off, 64);
    return v;
}
// quad reduction via DPP quad_perm (VALU-speed)
__device__ __forceinline__ float quadSum(float s) {
    int x = __builtin_amdgcn_mov_dpp(__float_as_int(s), 0xB1, 0xf, 0xf, true); // xor1
    s += __int_as_float(x);
    x = __builtin_amdgcn_mov_dpp(__float_as_int(s), 0x4E, 0xf, 0xf, true);     // xor2
    s += __int_as_float(x);
    return s;
}
__device__ __forceinline__ float waveMaxFast(float v) {
    int x = __builtin_amdgcn_mov_dpp(__float_as_int(v), 0xB1, 0xf, 0xf, true);
    v = fmaxf(v, __int_as_float(x));
    x = __builtin_amdgcn_mov_dpp(__float_as_int(v), 0x4E, 0xf, 0xf, true);
    v = fmaxf(v, __int_as_float(x));
#pragma unroll
    for (int off = 4; off <= 32; off <<= 1) v = fmaxf(v, __shfl_xor(v, off, 64));
    return v;
}

// ---- DPP primitives (all-VALU, no DS pipe) ----
template<int C> __device__ __forceinline__ float dppMax(float v) {
    int x = __builtin_amdgcn_mov_dpp(__float_as_int(v), C, 0xf, 0xf, true);
    return fmaxf(v, __int_as_float(x));
}
// wave max; result valid in lanes 32..63 (write from lane 63). All-DPP.
__device__ __forceinline__ float waveMaxTo63(float v) {
    v = dppMax<0xB1>(v);
    v = dppMax<0x4E>(v);
    v = dppMax<0x124>(v);
    v = dppMax<0x128>(v);   // each 16-row now holds row-max replicated
    v = dppMax<0x142>(v);   // row_bcast15
    v = dppMax<0x143>(v);   // row_bcast31 -> lanes 32..63 = full max
    return v;
}

// lgkm-only barrier: LDS visibility without draining global prefetch (vmcnt).
__device__ __forceinline__ void lds_barrier() {
    asm volatile("s_waitcnt lgkmcnt(0)\n\ts_barrier" ::: "memory");
}

#define PKFMA(ep, wp, acc) acc = __builtin_elementwise_fma(ep, wp, acc)

#define MATVEC_QUARTER(Wa, Wb, ev, sOut) {                          \
    const float4 e0 = ev[0], e1 = ev[1], e2 = ev[2], e3 = ev[3];    \
    const float4 e4 = ev[4], e5 = ev[5], e6 = ev[6], e7 = ev[7];    \
    f32x2 a0 = {0.f,0.f}, a1 = {0.f,0.f}, a2 = {0.f,0.f}, a3 = {0.f,0.f}; \
    PKFMA(((f32x2){e0.x, e0.y}), ((f32x2){Wa[0],  Wa[1]}),  a0);    \
    PKFMA(((f32x2){e0.z, e0.w}), ((f32x2){Wa[2],  Wa[3]}),  a1);    \
    PKFMA(((f32x2){e1.x, e1.y}), ((f32x2){Wa[4],  Wa[5]}),  a2);    \
    PKFMA(((f32x2){e1.z, e1.w}), ((f32x2){Wa[6],  Wa[7]}),  a3);    \
    PKFMA(((f32x2){e2.x, e2.y}), ((f32x2){Wa[8],  Wa[9]}),  a0);    \
    PKFMA(((f32x2){e2.z, e2.w}), ((f32x2){Wa[10], Wa[11]}), a1);    \
    PKFMA(((f32x2){e3.x, e3.y}), ((f32x2){Wa[12], Wa[13]}), a2);    \
    PKFMA(((f32x2){e3.z, e3.w}), ((f32x2){Wa[14], Wa[15]}), a3);    \
    PKFMA(((f32x2){e4.x, e4.y}), ((f32x2){Wb[0],  Wb[1]}),  a0);    \
    PKFMA(((f32x2){e4.z, e4.w}), ((f32x2){Wb[2],  Wb[3]}),  a1);    \
    PKFMA(((f32x2){e5.x, e5.y}), ((f32x2){Wb[4],  Wb[5]}),  a2);    \
    PKFMA(((f32x2){e5.z, e5.w}), ((f32x2){Wb[6],  Wb[7]}),  a3);    \
    PKFMA(((f32x2){e6.x, e6.y}), ((f32x2){Wb[8],  Wb[9]}),  a0);    \
    PKFMA(((f32x2){e6.z, e6.w}), ((f32x2){Wb[10], Wb[11]}), a1);    \
    PKFMA(((f32x2){e7.x, e7.y}), ((f32x2){Wb[12], Wb[13]}), a2);    \
    PKFMA(((f32x2){e7.z, e7.w}), ((f32x2){Wb[14], Wb[15]}), a3);    \
    const f32x2 s2 = (a0 + a1) + (a2 + a3);                         \
    sOut = s2[0] + s2[1]; }

// ---- W as 64 NAMED f32x2 registers, ASM-PINNED against rematerialization ----
// R2-R4 post-mortem (revised by R5/R6/R7 evidence): the allocator REMATERIALIZED
// the W init (sank the forb/trans loads+exp into the loop, re-loading 64 KB/
// step/CU from L1/L2) -- that, not spill, is why VGPR stayed 84 and per-step
// stayed ~2400 cyc across every source form. asm volatile("" : "+v"(x)) makes
// each W value an opaque asm output: it CANNOT be recomputed, so it must stay
// in a VGPR (or spill visibly). Budget: waves_per_eu(1,1) -> up to 512 VGPRs.
#define W_LIST(X) \
    X(0)  X(1)  X(2)  X(3)  X(4)  X(5)  X(6)  X(7)  \
    X(8)  X(9)  X(10) X(11) X(12) X(13) X(14) X(15) \
    X(16) X(17) X(18) X(19) X(20) X(21) X(22) X(23) \
    X(24) X(25) X(26) X(27) X(28) X(29) X(30) X(31) \
    X(32) X(33) X(34) X(35) X(36) X(37) X(38) X(39) \
    X(40) X(41) X(42) X(43) X(44) X(45) X(46) X(47) \
    X(48) X(49) X(50) X(51) X(52) X(53) X(54) X(55) \
    X(56) X(57) X(58) X(59) X(60) X(61) X(62) X(63)

#define WDECL(j) f32x2 W_##j;
#define WINIT_F(j) W_##j = (f32x2){ \
    forb[(2*(j)  )*KK + k] ? 0.0f : __expf(trans[(2*(j)  )*KK + k]), \
    forb[(2*(j)+1)*KK + k] ? 0.0f : __expf(trans[(2*(j)+1)*KK + k]) };
#define WINIT_B(j) W_##j = (f32x2){ \
    forb[k*KK + 2*(j)  ] ? 0.0f : __expf(trans[k*KK + 2*(j)  ]), \
    forb[k*KK + 2*(j)+1] ? 0.0f : __expf(trans[k*KK + 2*(j)+1]) };
#define WPIN(j) asm volatile("" : "+v"(W_##j));
#define WFMA(j, p0, p1, A0, A1) { const float4 E = ev[(j)]; \
    PKFMA(((f32x2){E.x, E.y}), W_##p0, A0); \
    PKFMA(((f32x2){E.z, E.w}), W_##p1, A1); }

// Forward/backward meet-in-the-middle. Skeleton = R6 (proven 855us): 2 waves,
// chunked composed-bi staging (globally-quiet inner loop), per-step lgkm-only
// barrier. NEW: W in VGPRs (asm-pinned), so the inner loop's DS traffic is
// only 32 uniform e-broadcast b128 + 1 bi b32 + 1 ds_write_b32 per wave.
extern "C" __global__ __launch_bounds__(128, 1)
__attribute__((amdgpu_waves_per_eu(1, 1)))
void crf_fb_kernel(const float* __restrict__ em,
                   const int* __restrict__ mask,
                   const int* __restrict__ tgt,
                   const float* __restrict__ trans,
                   const float* __restrict__ start,
                   const int* __restrict__ forb,
                   float* __restrict__ ef,      // [128][KK] forward exp-alpha
                   float* __restrict__ db,      // [128][KK] backward exp-beta
                   float* __restrict__ Mfb)     // [256] scales: fwd 0..127, bwd 128..255
{
    const int tid  = threadIdx.x;       // 0..127 == output state k
    const int k    = tid;
    const int w    = tid >> 6;
    const int lane = tid & 63;
    const bool fwdDir = (blockIdx.x < 2 * BB);
    const int c    = blockIdx.x & (2 * BB - 1);
    const int b    = c & (BB - 1);
    const bool sup = (c < BB);

    __shared__ __align__(16) float biLDS[2][CH][KK]; // 32 KB composed bi chunks
    __shared__ __align__(16) float eLDS[2][KK];
    __shared__ __align__(8)  float wmLDS[2];
    __shared__ float redLDS[2];
    __shared__ int lenLDS;

    // ---- length ----
    if (tid == 0) lenLDS = 0;
    int ps = 0;
    const int4* __restrict__ mrow = (const int4*)(mask + (size_t)b * TT);
#pragma unroll
    for (int it = 0; it < 4; ++it) {
        const int4 m4 = mrow[tid + 128 * it];
        ps += m4.x + m4.y + m4.z + m4.w;
    }
    ps = waveSumI(ps);
    __syncthreads();                     // lenLDS zeroed before adds
    if (lane == 0) atomicAdd(&lenLDS, ps);

    const float st = start[k];
    const float* __restrict__ emrow = em + (size_t)b * TT * KK;
    const int* __restrict__ trow = tgt + (size_t)b * TT * KK;

    // ---- W in named registers, then pin ----
    W_LIST(WDECL)
    if (fwdDir) {
        W_LIST(WINIT_F)
    } else {
        W_LIST(WINIT_B)
    }
    W_LIST(WPIN)                         // opaque: no remat, must stay in VGPR
    __syncthreads();                     // lenLDS ready
    const int len = lenLDS;              // uniform, in [1024, 2048]
    const int mid = len >> 1;
    const int N   = fwdDir ? mid : (len - 1 - mid);   // serial steps (>=511)
    const int t0  = fwdDir ? 0 : (len - 1);

    // ---- init vector at t0: exact max renorm ----
    float v0 = emrow[(size_t)t0 * KK + k];
    if (sup && !trow[(size_t)t0 * KK + k]) v0 = -100000.0f;
    v0 += st;
    const float wm0 = waveMax(v0);
    if (lane == 0) redLDS[w] = wm0;
    __syncthreads();
    const float M0 = fmaxf(redLDS[0], redLDS[1]);
    double M = (double)M0;
    float eNew = __expf(v0 - M0);
    eLDS[0][k] = eNew;

    // ---- chunked composed-bi staging (R6, proven) ----
    const int scol = (tid & 31) << 2;
    const float4 stc = *(const float4*)(start + scol);
    auto stageChunk = [&](int bf, int m) {
        const int base_n = 1 + CH * m;
        const int t_base = fwdDir ? base_n : (len - base_n - CH);
#pragma unroll
        for (int i = 0; i < 8; ++i) {
            const int row = (tid >> 5) + (i << 2);
            const int t = t_base + row;
            float4 e4 = *(const float4*)(emrow + (size_t)t * KK + scol);
            if (sup) {
                const int4 t4 = *(const int4*)(trow + (size_t)t * KK + scol);
                e4.x = t4.x ? e4.x : -100000.0f;
                e4.y = t4.y ? e4.y : -100000.0f;
                e4.z = t4.z ? e4.z : -100000.0f;
                e4.w = t4.w ? e4.w : -100000.0f;
            }
            e4.x += stc.x; e4.y += stc.y; e4.z += stc.z; e4.w += stc.w;
            *(float4*)&biLDS[bf][row][scol] = e4;
        }
    };

    const int nChunks = (N + CH - 1) / CH;
    int buf = 0;
    stageChunk(0, 0);
    lds_barrier();                       // publish eLDS[0] + biLDS[0]

    for (int m = 0; m < nChunks; ++m) {
        if (m + 1 < nChunks) stageChunk(buf ^ 1, m + 1);
        const int base_n = 1 + CH * m;
        const int rem = N - base_n + 1;
        const int lim = rem < CH ? rem : CH;
#pragma unroll 4
        for (int i = 0; i < lim; ++i) {
            const int n = base_n + i;
            const int p = (n - 1) & 1;

            // bi from LDS (2-way aliasing: free). bwd final step: bi=0.
            const int pos = fwdDir ? i : (CH - 1 - i);
            float bi = biLDS[buf][pos][k];
            if (!fwdDir && n == N) bi = 0.0f;

            // block-renorm (proven cadence): measure at n%4==3, apply n%4==0.
            if ((n & 3) == 3) {
                const float u = waveMaxTo63(__logf(eNew));
                if (lane == 63) wmLDS[w] = u;
            }
            float r = 0.0f;
            if ((n & 3) == 0) {
                const float2 wmv = *(const float2*)wmLDS;  // uniform b64 bcast
                r = fmaxf(wmv.x, wmv.y);
                M += (double)r;
            }
            const float f = __expf(bi - r);  // overlaps matvec

            // full 128-input dot product: e uniform-broadcast b128, W in VGPRs
            const float4* __restrict__ ev = (const float4*)eLDS[p];
            f32x2 a0 = {0.f,0.f}, a1 = {0.f,0.f}, a2 = {0.f,0.f}, a3 = {0.f,0.f};
            WFMA( 0,  0,  1, a0, a1) WFMA( 1,  2,  3, a2, a3)
            WFMA( 2,  4,  5, a0, a1) WFMA( 3,  6,  7, a2, a3)
            WFMA( 4,  8,  9, a0, a1) WFMA( 5, 10, 11, a2, a3)
            WFMA( 6, 12, 13, a0, a1) WFMA( 7, 14, 15, a2, a3)
            WFMA( 8, 16, 17, a0, a1) WFMA( 9, 18, 19, a2, a3)
            WFMA(10, 20, 21, a0, a1) WFMA(11, 22, 23, a2, a3)
            WFMA(12, 24, 25, a0, a1) WFMA(13, 26, 27, a2, a3)
            WFMA(14, 28, 29, a0, a1) WFMA(15, 30, 31, a2, a3)
            WFMA(16, 32, 33, a0, a1) WFMA(17, 34, 35, a2, a3)
            WFMA(18, 36, 37, a0, a1) WFMA(19, 38, 39, a2, a3)
            WFMA(20, 40, 41, a0, a1) WFMA(21, 42, 43, a2, a3)
            WFMA(22, 44, 45, a0, a1) WFMA(23, 46, 47, a2, a3)
            WFMA(24, 48, 49, a0, a1) WFMA(25, 50, 51, a2, a3)
            WFMA(26, 52, 53, a0, a1) WFMA(27, 54, 55, a2, a3)
            WFMA(28, 56, 57, a0, a1) WFMA(29, 58, 59, a2, a3)
            WFMA(30, 60, 61, a0, a1) WFMA(31, 62, 63, a2, a3)
            const f32x2 aa = (a0 + a1) + (a2 + a3);
            const float s = aa[0] + aa[1];

            eNew = s * f;
            eLDS[p ^ 1][k] = eNew;           // 1 ds_write_b32, conflict-free

            lds_barrier();                   // globally-quiet inner barrier
        }
        buf ^= 1;
    }

    (fwdDir ? ef : db)[(size_t)c * KK + k] = eNew;
    if (tid == 0) Mfb[(fwdDir ? 0 : 2 * BB) + c] = (float)M;
}

// z[c] = Mf[c] + Mb[c] + log(dot(ef[c], db[c])); out[b] = z[b] - z[b+64]
extern "C" __global__ void crf_combine_kernel(const float* __restrict__ ef,
                                              const float* __restrict__ db,
                                              const float* __restrict__ Mfb,
                                              float* __restrict__ out)
{
    const int b = blockIdx.x;
    const int tid = threadIdx.x;         // 0..127 = state
    const int wv = tid >> 6, lane = tid & 63;
    __shared__ float red[2][2];
    __shared__ float z[2];
#pragma unroll
    for (int s = 0; s < 2; ++s) {
        const int c = b + s * BB;
        const float v = ef[(size_t)c * KK + tid] * db[(size_t)c * KK + tid];
        const float p = waveSum(v);
        if (lane == 0) red[s][wv] = p;
    }
    __syncthreads();
    if (tid < 2) {
        const int c = b + tid * BB;
        z[tid] = Mfb[c] + Mfb[2 * BB + c] + __logf(red[tid][0] + red[tid][1]);
    }
    __syncthreads();
    if (tid == 0) out[b] = z[0] - z[1];
}

// ---------------- fallback (proven): used only if ws is too small ----------
extern "C" __global__ __launch_bounds__(512)
__attribute__((amdgpu_waves_per_eu(2, 2)))
void crf_chain_kernel(const float* __restrict__ em, const int* __restrict__ mask,
                      const int* __restrict__ tgt, const float* __restrict__ trans,
                      const float* __restrict__ start, const int* __restrict__ forb,
                      float* __restrict__ zbuf)
{
    const int tid = threadIdx.x;
    const int k = tid >> 2, q = tid & 3, w = tid >> 6, lane = tid & 63;
    const int c = blockIdx.x, b = c & (BB - 1);
    const bool sup = (c < BB);
    __shared__ __align__(16) float eLDS[2][KK];
    __shared__ float wmLDS[8];
    __shared__ float redLDS[8];
    __shared__ int lenLDS;
    if (tid == 0) lenLDS = 0;
    const int4 m4 = ((const int4*)(mask + (size_t)b * TT))[tid];
    int ps = m4.x + m4.y + m4.z + m4.w;
    ps = waveSumI(ps);
    __syncthreads();
    if (lane == 0) atomicAdd(&lenLDS, ps);
    const float st = start[k];
    const float* __restrict__ emrow = em + (size_t)b * TT * KK;
    const int* __restrict__ trow = tgt + (size_t)b * TT * KK;
    const int ib = q * 32;
    f32x16 Wa, Wb;
#pragma unroll
    for (int j = 0; j < 16; ++j) {
        Wa[j] = forb[(ib + j     ) * KK + k] ? 0.0f : __expf(trans[(ib + j     ) * KK + k]);
        Wb[j] = forb[(ib + 16 + j) * KK + k] ? 0.0f : __expf(trans[(ib + 16 + j) * KK + k]);
    }
    float v0 = emrow[k];
    if (sup && !trow[k]) v0 = -100000.0f;
    v0 += st;
    const float wm0 = waveMax(v0);
    if (lane == 0) redLDS[w] = wm0;
    __syncthreads();
    const int len = lenLDS;
    float M0 = fmaxf(fmaxf(fmaxf(redLDS[0], redLDS[1]), fmaxf(redLDS[2], redLDS[3])),
                     fmaxf(fmaxf(redLDS[4], redLDS[5]), fmaxf(redLDS[6], redLDS[7])));
    double M = (double)M0;
    float eNew = __expf(v0 - M0);
    if (q == 0) eLDS[0][k] = eNew;
    auto bival = [&](int t) -> float {
        float e0 = emrow[(size_t)t * KK + k];
        if (sup) { if (!trow[(size_t)t * KK + k]) e0 = -100000.0f; }
        return e0 + st;
    };
    float biA = (len > 1) ? bival(1) : 0.0f;
    float biB = (len > 2) ? bival(2) : 0.0f;
    float biC = (len > 3) ? bival(3) : 0.0f;
    float biD = (len > 4) ? bival(4) : 0.0f;
    float sPrev = 1.0f, baPrev = 0.0f;
    lds_barrier();
#pragma unroll 4
    for (int t = 1; t < len; ++t) {
        const int p = (t - 1) & 1;
        const float biN = (t + 4 < len) ? bival(t + 4) : 0.0f;
        if ((t & 3) == 3) {
            const float u = __logf(sPrev) + baPrev;
            const float wmx = waveMaxFast(u);
            if (lane == 0) wmLDS[w] = wmx;
        }
        float r = 0.0f;
        if ((t & 3) == 0) {
            r = fmaxf(fmaxf(fmaxf(wmLDS[0], wmLDS[1]), fmaxf(wmLDS[2], wmLDS[3])),
                      fmaxf(fmaxf(wmLDS[4], wmLDS[5]), fmaxf(wmLDS[6], wmLDS[7])));
            M += (double)r;
        }
        const float ba = biA - r;
        const float f = __expf(ba);
        const float4* __restrict__ ev = (const float4*)eLDS[p] + q * 8;
        float s;
        MATVEC_QUARTER(Wa, Wb, ev, s)
        s = quadSum(s);
        eNew = s * f;
        if (q == 0) eLDS[p ^ 1][k] = eNew;
        sPrev = s; baPrev = ba;
        biA = biB; biB = biC; biC = biD; biD = biN;
        lds_barrier();
    }
    const float sm = waveSum((q == 0) ? eNew : 0.0f);
    if (lane == 0) redLDS[w] = sm;
    __syncthreads();
    if (tid == 0) {
        const float ss = ((redLDS[0] + redLDS[1]) + (redLDS[2] + redLDS[3]))
                       + ((redLDS[4] + redLDS[5]) + (redLDS[6] + redLDS[7]));
        zbuf[c] = (float)(M + (double)__logf(ss));
    }
}

extern "C" __global__ void crf_final_kernel(const float* __restrict__ z,
                                            float* __restrict__ out)
{
    const int b = threadIdx.x;
    out[b] = z[b] - z[b + BB];
}

extern "C" void kernel_launch(void* const* d_in, const int* in_sizes, int n_in,
                              void* d_out, int out_size, void* d_ws, size_t ws_size,
                              hipStream_t stream) {
    const float* em    = (const float*)d_in[0];
    const int*   mask  = (const int*)d_in[1];
    const int*   tgt   = (const int*)d_in[2];
    const float* trans = (const float*)d_in[3];
    const float* start = (const float*)d_in[4];
    const int*   forb  = (const int*)d_in[5];

    const size_t need = (size_t)(2 * 2 * BB * KK + 4 * BB) * sizeof(float); // 132 KB
    if (ws_size >= need) {
        float* ef  = (float*)d_ws;                       // [128][128]
        float* db  = ef + 2 * BB * KK;                   // [128][128]
        float* Mfb = db + 2 * BB * KK;                   // [256]
        crf_fb_kernel<<<4 * BB, 128, 0, stream>>>(em, mask, tgt, trans, start,
                                                  forb, ef, db, Mfb);
        crf_combine_kernel<<<BB, 128, 0, stream>>>(ef, db, Mfb, (float*)d_out);
    } else {
        float* zbuf = (float*)d_ws;
        crf_chain_kernel<<<2 * BB, 512, 0, stream>>>(em, mask, tgt, trans, start,
                                                     forb, zbuf);
        crf_final_kernel<<<1, BB, 0, stream>>>(zbuf, (float*)d_out);
    }
}

// Round 9
// 819.144 us; speedup vs baseline: 1.7150x; 1.0145x over previous
//
#include <hip/hip_runtime.h>
#include <stdint.h>

#define BB 64
#define TT 2048
#define KK 128
#define CH 32         // bi-staging chunk: steps per chunk

typedef float f32x16 __attribute__((ext_vector_type(16)));
typedef float f32x2  __attribute__((ext_vector_type(2)));

__device__ __forceinline__ float waveMax(float v) {
#pragma unroll
    for (int off = 32; off; off >>= 1) v = fmaxf(v, __shfl_xor(v, off, 64));
    return v;
}
__device__ __forceinline__ float waveSum(float v) {
#pragma unroll
    for (int off = 32; off; off >>= 1) v += __shfl_xor(v, off, 64);
    return v;
}
__device__ __forceinline__ int waveSumI(int v) {
#pragma unroll
    for (int off = 32; off; off >>= 1) v += __shfl_xor(v, off, 64);
    return v;
}
// quad reduction via DPP quad_perm (VALU-speed)
__device__ __forceinline__ float quadSum(float s) {
    int x = __builtin_amdgcn_mov_dpp(__float_as_int(s), 0xB1, 0xf, 0xf, true); // xor1
    s += __int_as_float(x);
    x = __builtin_amdgcn_mov_dpp(__float_as_int(s), 0x4E, 0xf, 0xf, true);     // xor2
    s += __int_as_float(x);
    return s;
}
__device__ __forceinline__ float waveMaxFast(float v) {
    int x = __builtin_amdgcn_mov_dpp(__float_as_int(v), 0xB1, 0xf, 0xf, true);
    v = fmaxf(v, __int_as_float(x));
    x = __builtin_amdgcn_mov_dpp(__float_as_int(v), 0x4E, 0xf, 0xf, true);
    v = fmaxf(v, __int_as_float(x));
#pragma unroll
    for (int off = 4; off <= 32; off <<= 1) v = fmaxf(v, __shfl_xor(v, off, 64));
    return v;
}

// ---- DPP primitives (all-VALU, no DS pipe) ----
template<int C> __device__ __forceinline__ float dppMax(float v) {
    int x = __builtin_amdgcn_mov_dpp(__float_as_int(v), C, 0xf, 0xf, true);
    return fmaxf(v, __int_as_float(x));
}
// wave max; result valid in lanes 32..63 (write from lane 63). All-DPP.
__device__ __forceinline__ float waveMaxTo63(float v) {
    v = dppMax<0xB1>(v);
    v = dppMax<0x4E>(v);
    v = dppMax<0x124>(v);
    v = dppMax<0x128>(v);   // each 16-row now holds row-max replicated
    v = dppMax<0x142>(v);   // row_bcast15
    v = dppMax<0x143>(v);   // row_bcast31 -> lanes 32..63 = full max
    return v;
}

// lgkm-only barrier: LDS visibility without draining global prefetch (vmcnt).
__device__ __forceinline__ void lds_barrier() {
    asm volatile("s_waitcnt lgkmcnt(0)\n\ts_barrier" ::: "memory");
}

#define PKFMA(ep, wp, acc) acc = __builtin_elementwise_fma(ep, wp, acc)

#define MATVEC_QUARTER(Wa, Wb, ev, sOut) {                          \
    const float4 e0 = ev[0], e1 = ev[1], e2 = ev[2], e3 = ev[3];    \
    const float4 e4 = ev[4], e5 = ev[5], e6 = ev[6], e7 = ev[7];    \
    f32x2 a0 = {0.f,0.f}, a1 = {0.f,0.f}, a2 = {0.f,0.f}, a3 = {0.f,0.f}; \
    PKFMA(((f32x2){e0.x, e0.y}), ((f32x2){Wa[0],  Wa[1]}),  a0);    \
    PKFMA(((f32x2){e0.z, e0.w}), ((f32x2){Wa[2],  Wa[3]}),  a1);    \
    PKFMA(((f32x2){e1.x, e1.y}), ((f32x2){Wa[4],  Wa[5]}),  a2);    \
    PKFMA(((f32x2){e1.z, e1.w}), ((f32x2){Wa[6],  Wa[7]}),  a3);    \
    PKFMA(((f32x2){e2.x, e2.y}), ((f32x2){Wa[8],  Wa[9]}),  a0);    \
    PKFMA(((f32x2){e2.z, e2.w}), ((f32x2){Wa[10], Wa[11]}), a1);    \
    PKFMA(((f32x2){e3.x, e3.y}), ((f32x2){Wa[12], Wa[13]}), a2);    \
    PKFMA(((f32x2){e3.z, e3.w}), ((f32x2){Wa[14], Wa[15]}), a3);    \
    PKFMA(((f32x2){e4.x, e4.y}), ((f32x2){Wb[0],  Wb[1]}),  a0);    \
    PKFMA(((f32x2){e4.z, e4.w}), ((f32x2){Wb[2],  Wb[3]}),  a1);    \
    PKFMA(((f32x2){e5.x, e5.y}), ((f32x2){Wb[4],  Wb[5]}),  a2);    \
    PKFMA(((f32x2){e5.z, e5.w}), ((f32x2){Wb[6],  Wb[7]}),  a3);    \
    PKFMA(((f32x2){e6.x, e6.y}), ((f32x2){Wb[8],  Wb[9]}),  a0);    \
    PKFMA(((f32x2){e6.z, e6.w}), ((f32x2){Wb[10], Wb[11]}), a1);    \
    PKFMA(((f32x2){e7.x, e7.y}), ((f32x2){Wb[12], Wb[13]}), a2);    \
    PKFMA(((f32x2){e7.z, e7.w}), ((f32x2){Wb[14], Wb[15]}), a3);    \
    const f32x2 s2 = (a0 + a1) + (a2 + a3);                         \
    sOut = s2[0] + s2[1]; }

// ---- W as 64 NAMED f32x2 values pinned into AGPRs ----
// R8 post-mortem: "+v" pin kept only ~half of W resident (VGPR_Count=92 < 128
// needed); the allocator spilled the rest to L1/L2-backed scratch and the loop
// still streams ~64 KB/step/CU -- the 1717 cyc/step floor. THIS round: pin W
// into the AGPR half of gfx950's unified file ("+a" constraint). AGPRs exist
// precisely for long-lived per-lane state; gfx90a+ VALU can source AGPRs (or
// the compiler inserts 1-cyc v_accvgpr_read), so worst case ~256 cyc/wave of
// moves replaces ~1000+ cyc of cache streaming.
#define W_LIST(X) \
    X(0)  X(1)  X(2)  X(3)  X(4)  X(5)  X(6)  X(7)  \
    X(8)  X(9)  X(10) X(11) X(12) X(13) X(14) X(15) \
    X(16) X(17) X(18) X(19) X(20) X(21) X(22) X(23) \
    X(24) X(25) X(26) X(27) X(28) X(29) X(30) X(31) \
    X(32) X(33) X(34) X(35) X(36) X(37) X(38) X(39) \
    X(40) X(41) X(42) X(43) X(44) X(45) X(46) X(47) \
    X(48) X(49) X(50) X(51) X(52) X(53) X(54) X(55) \
    X(56) X(57) X(58) X(59) X(60) X(61) X(62) X(63)

#define WDECL(j) f32x2 W_##j;
#define WINIT_F(j) W_##j = (f32x2){ \
    forb[(2*(j)  )*KK + k] ? 0.0f : __expf(trans[(2*(j)  )*KK + k]), \
    forb[(2*(j)+1)*KK + k] ? 0.0f : __expf(trans[(2*(j)+1)*KK + k]) };
#define WINIT_B(j) W_##j = (f32x2){ \
    forb[k*KK + 2*(j)  ] ? 0.0f : __expf(trans[k*KK + 2*(j)  ]), \
    forb[k*KK + 2*(j)+1] ? 0.0f : __expf(trans[k*KK + 2*(j)+1]) };
#define WPIN(j) asm volatile("" : "+a"(W_##j));   // AGPR-resident, no remat
#define WFMA(j, p0, p1, A0, A1) { const float4 E = ev[(j)]; \
    PKFMA(((f32x2){E.x, E.y}), W_##p0, A0); \
    PKFMA(((f32x2){E.z, E.w}), W_##p1, A1); }

// Forward/backward meet-in-the-middle. Skeleton = R8 (proven 733us): 2 waves,
// chunked composed-bi staging (globally-quiet inner loop), per-step lgkm-only
// barrier; only the W pin constraint changed ("+v" -> "+a").
extern "C" __global__ __launch_bounds__(128, 1)
__attribute__((amdgpu_waves_per_eu(1, 1)))
void crf_fb_kernel(const float* __restrict__ em,
                   const int* __restrict__ mask,
                   const int* __restrict__ tgt,
                   const float* __restrict__ trans,
                   const float* __restrict__ start,
                   const int* __restrict__ forb,
                   float* __restrict__ ef,      // [128][KK] forward exp-alpha
                   float* __restrict__ db,      // [128][KK] backward exp-beta
                   float* __restrict__ Mfb)     // [256] scales: fwd 0..127, bwd 128..255
{
    const int tid  = threadIdx.x;       // 0..127 == output state k
    const int k    = tid;
    const int w    = tid >> 6;
    const int lane = tid & 63;
    const bool fwdDir = (blockIdx.x < 2 * BB);
    const int c    = blockIdx.x & (2 * BB - 1);
    const int b    = c & (BB - 1);
    const bool sup = (c < BB);

    __shared__ __align__(16) float biLDS[2][CH][KK]; // 32 KB composed bi chunks
    __shared__ __align__(16) float eLDS[2][KK];
    __shared__ __align__(8)  float wmLDS[2];
    __shared__ float redLDS[2];
    __shared__ int lenLDS;

    // ---- length ----
    if (tid == 0) lenLDS = 0;
    int ps = 0;
    const int4* __restrict__ mrow = (const int4*)(mask + (size_t)b * TT);
#pragma unroll
    for (int it = 0; it < 4; ++it) {
        const int4 m4 = mrow[tid + 128 * it];
        ps += m4.x + m4.y + m4.z + m4.w;
    }
    ps = waveSumI(ps);
    __syncthreads();                     // lenLDS zeroed before adds
    if (lane == 0) atomicAdd(&lenLDS, ps);

    const float st = start[k];
    const float* __restrict__ emrow = em + (size_t)b * TT * KK;
    const int* __restrict__ trow = tgt + (size_t)b * TT * KK;

    // ---- W in named values, then pin into AGPRs ----
    W_LIST(WDECL)
    if (fwdDir) {
        W_LIST(WINIT_F)
    } else {
        W_LIST(WINIT_B)
    }
    W_LIST(WPIN)                         // opaque + AGPR class: stays resident
    __syncthreads();                     // lenLDS ready
    const int len = lenLDS;              // uniform, in [1024, 2048]
    const int mid = len >> 1;
    const int N   = fwdDir ? mid : (len - 1 - mid);   // serial steps (>=511)
    const int t0  = fwdDir ? 0 : (len - 1);

    // ---- init vector at t0: exact max renorm ----
    float v0 = emrow[(size_t)t0 * KK + k];
    if (sup && !trow[(size_t)t0 * KK + k]) v0 = -100000.0f;
    v0 += st;
    const float wm0 = waveMax(v0);
    if (lane == 0) redLDS[w] = wm0;
    __syncthreads();
    const float M0 = fmaxf(redLDS[0], redLDS[1]);
    double M = (double)M0;
    float eNew = __expf(v0 - M0);
    eLDS[0][k] = eNew;

    // ---- chunked composed-bi staging (R6, proven) ----
    const int scol = (tid & 31) << 2;
    const float4 stc = *(const float4*)(start + scol);
    auto stageChunk = [&](int bf, int m) {
        const int base_n = 1 + CH * m;
        const int t_base = fwdDir ? base_n : (len - base_n - CH);
#pragma unroll
        for (int i = 0; i < 8; ++i) {
            const int row = (tid >> 5) + (i << 2);
            const int t = t_base + row;
            float4 e4 = *(const float4*)(emrow + (size_t)t * KK + scol);
            if (sup) {
                const int4 t4 = *(const int4*)(trow + (size_t)t * KK + scol);
                e4.x = t4.x ? e4.x : -100000.0f;
                e4.y = t4.y ? e4.y : -100000.0f;
                e4.z = t4.z ? e4.z : -100000.0f;
                e4.w = t4.w ? e4.w : -100000.0f;
            }
            e4.x += stc.x; e4.y += stc.y; e4.z += stc.z; e4.w += stc.w;
            *(float4*)&biLDS[bf][row][scol] = e4;
        }
    };

    const int nChunks = (N + CH - 1) / CH;
    int buf = 0;
    stageChunk(0, 0);
    lds_barrier();                       // publish eLDS[0] + biLDS[0]

    for (int m = 0; m < nChunks; ++m) {
        if (m + 1 < nChunks) stageChunk(buf ^ 1, m + 1);
        const int base_n = 1 + CH * m;
        const int rem = N - base_n + 1;
        const int lim = rem < CH ? rem : CH;
#pragma unroll 4
        for (int i = 0; i < lim; ++i) {
            const int n = base_n + i;
            const int p = (n - 1) & 1;

            // bi from LDS (2-way aliasing: free). bwd final step: bi=0.
            const int pos = fwdDir ? i : (CH - 1 - i);
            float bi = biLDS[buf][pos][k];
            if (!fwdDir && n == N) bi = 0.0f;

            // block-renorm (proven cadence): measure at n%4==3, apply n%4==0.
            if ((n & 3) == 3) {
                const float u = waveMaxTo63(__logf(eNew));
                if (lane == 63) wmLDS[w] = u;
            }
            float r = 0.0f;
            if ((n & 3) == 0) {
                const float2 wmv = *(const float2*)wmLDS;  // uniform b64 bcast
                r = fmaxf(wmv.x, wmv.y);
                M += (double)r;
            }
            const float f = __expf(bi - r);  // overlaps matvec

            // full 128-input dot product: e uniform-broadcast b128, W in AGPRs
            const float4* __restrict__ ev = (const float4*)eLDS[p];
            f32x2 a0 = {0.f,0.f}, a1 = {0.f,0.f}, a2 = {0.f,0.f}, a3 = {0.f,0.f};
            WFMA( 0,  0,  1, a0, a1) WFMA( 1,  2,  3, a2, a3)
            WFMA( 2,  4,  5, a0, a1) WFMA( 3,  6,  7, a2, a3)
            WFMA( 4,  8,  9, a0, a1) WFMA( 5, 10, 11, a2, a3)
            WFMA( 6, 12, 13, a0, a1) WFMA( 7, 14, 15, a2, a3)
            WFMA( 8, 16, 17, a0, a1) WFMA( 9, 18, 19, a2, a3)
            WFMA(10, 20, 21, a0, a1) WFMA(11, 22, 23, a2, a3)
            WFMA(12, 24, 25, a0, a1) WFMA(13, 26, 27, a2, a3)
            WFMA(14, 28, 29, a0, a1) WFMA(15, 30, 31, a2, a3)
            WFMA(16, 32, 33, a0, a1) WFMA(17, 34, 35, a2, a3)
            WFMA(18, 36, 37, a0, a1) WFMA(19, 38, 39, a2, a3)
            WFMA(20, 40, 41, a0, a1) WFMA(21, 42, 43, a2, a3)
            WFMA(22, 44, 45, a0, a1) WFMA(23, 46, 47, a2, a3)
            WFMA(24, 48, 49, a0, a1) WFMA(25, 50, 51, a2, a3)
            WFMA(26, 52, 53, a0, a1) WFMA(27, 54, 55, a2, a3)
            WFMA(28, 56, 57, a0, a1) WFMA(29, 58, 59, a2, a3)
            WFMA(30, 60, 61, a0, a1) WFMA(31, 62, 63, a2, a3)
            const f32x2 aa = (a0 + a1) + (a2 + a3);
            const float s = aa[0] + aa[1];

            eNew = s * f;
            eLDS[p ^ 1][k] = eNew;           // 1 ds_write_b32, conflict-free

            lds_barrier();                   // globally-quiet inner barrier
        }
        buf ^= 1;
    }

    (fwdDir ? ef : db)[(size_t)c * KK + k] = eNew;
    if (tid == 0) Mfb[(fwdDir ? 0 : 2 * BB) + c] = (float)M;
}

// z[c] = Mf[c] + Mb[c] + log(dot(ef[c], db[c])); out[b] = z[b] - z[b+64]
extern "C" __global__ void crf_combine_kernel(const float* __restrict__ ef,
                                              const float* __restrict__ db,
                                              const float* __restrict__ Mfb,
                                              float* __restrict__ out)
{
    const int b = blockIdx.x;
    const int tid = threadIdx.x;         // 0..127 = state
    const int wv = tid >> 6, lane = tid & 63;
    __shared__ float red[2][2];
    __shared__ float z[2];
#pragma unroll
    for (int s = 0; s < 2; ++s) {
        const int c = b + s * BB;
        const float v = ef[(size_t)c * KK + tid] * db[(size_t)c * KK + tid];
        const float p = waveSum(v);
        if (lane == 0) red[s][wv] = p;
    }
    __syncthreads();
    if (tid < 2) {
        const int c = b + tid * BB;
        z[tid] = Mfb[c] + Mfb[2 * BB + c] + __logf(red[tid][0] + red[tid][1]);
    }
    __syncthreads();
    if (tid == 0) out[b] = z[0] - z[1];
}

// ---------------- fallback (proven): used only if ws is too small ----------
extern "C" __global__ __launch_bounds__(512)
__attribute__((amdgpu_waves_per_eu(2, 2)))
void crf_chain_kernel(const float* __restrict__ em, const int* __restrict__ mask,
                      const int* __restrict__ tgt, const float* __restrict__ trans,
                      const float* __restrict__ start, const int* __restrict__ forb,
                      float* __restrict__ zbuf)
{
    const int tid = threadIdx.x;
    const int k = tid >> 2, q = tid & 3, w = tid >> 6, lane = tid & 63;
    const int c = blockIdx.x, b = c & (BB - 1);
    const bool sup = (c < BB);
    __shared__ __align__(16) float eLDS[2][KK];
    __shared__ float wmLDS[8];
    __shared__ float redLDS[8];
    __shared__ int lenLDS;
    if (tid == 0) lenLDS = 0;
    const int4 m4 = ((const int4*)(mask + (size_t)b * TT))[tid];
    int ps = m4.x + m4.y + m4.z + m4.w;
    ps = waveSumI(ps);
    __syncthreads();
    if (lane == 0) atomicAdd(&lenLDS, ps);
    const float st = start[k];
    const float* __restrict__ emrow = em + (size_t)b * TT * KK;
    const int* __restrict__ trow = tgt + (size_t)b * TT * KK;
    const int ib = q * 32;
    f32x16 Wa, Wb;
#pragma unroll
    for (int j = 0; j < 16; ++j) {
        Wa[j] = forb[(ib + j     ) * KK + k] ? 0.0f : __expf(trans[(ib + j     ) * KK + k]);
        Wb[j] = forb[(ib + 16 + j) * KK + k] ? 0.0f : __expf(trans[(ib + 16 + j) * KK + k]);
    }
    float v0 = emrow[k];
    if (sup && !trow[k]) v0 = -100000.0f;
    v0 += st;
    const float wm0 = waveMax(v0);
    if (lane == 0) redLDS[w] = wm0;
    __syncthreads();
    const int len = lenLDS;
    float M0 = fmaxf(fmaxf(fmaxf(redLDS[0], redLDS[1]), fmaxf(redLDS[2], redLDS[3])),
                     fmaxf(fmaxf(redLDS[4], redLDS[5]), fmaxf(redLDS[6], redLDS[7])));
    double M = (double)M0;
    float eNew = __expf(v0 - M0);
    if (q == 0) eLDS[0][k] = eNew;
    auto bival = [&](int t) -> float {
        float e0 = emrow[(size_t)t * KK + k];
        if (sup) { if (!trow[(size_t)t * KK + k]) e0 = -100000.0f; }
        return e0 + st;
    };
    float biA = (len > 1) ? bival(1) : 0.0f;
    float biB = (len > 2) ? bival(2) : 0.0f;
    float biC = (len > 3) ? bival(3) : 0.0f;
    float biD = (len > 4) ? bival(4) : 0.0f;
    float sPrev = 1.0f, baPrev = 0.0f;
    lds_barrier();
#pragma unroll 4
    for (int t = 1; t < len; ++t) {
        const int p = (t - 1) & 1;
        const float biN = (t + 4 < len) ? bival(t + 4) : 0.0f;
        if ((t & 3) == 3) {
            const float u = __logf(sPrev) + baPrev;
            const float wmx = waveMaxFast(u);
            if (lane == 0) wmLDS[w] = wmx;
        }
        float r = 0.0f;
        if ((t & 3) == 0) {
            r = fmaxf(fmaxf(fmaxf(wmLDS[0], wmLDS[1]), fmaxf(wmLDS[2], wmLDS[3])),
                      fmaxf(fmaxf(wmLDS[4], wmLDS[5]), fmaxf(wmLDS[6], wmLDS[7])));
            M += (double)r;
        }
        const float ba = biA - r;
        const float f = __expf(ba);
        const float4* __restrict__ ev = (const float4*)eLDS[p] + q * 8;
        float s;
        MATVEC_QUARTER(Wa, Wb, ev, s)
        s = quadSum(s);
        eNew = s * f;
        if (q == 0) eLDS[p ^ 1][k] = eNew;
        sPrev = s; baPrev = ba;
        biA = biB; biB = biC; biC = biD; biD = biN;
        lds_barrier();
    }
    const float sm = waveSum((q == 0) ? eNew : 0.0f);
    if (lane == 0) redLDS[w] = sm;
    __syncthreads();
    if (tid == 0) {
        const float ss = ((redLDS[0] + redLDS[1]) + (redLDS[2] + redLDS[3]))
                       + ((redLDS[4] + redLDS[5]) + (redLDS[6] + redLDS[7]));
        zbuf[c] = (float)(M + (double)__logf(ss));
    }
}

extern "C" __global__ void crf_final_kernel(const float* __restrict__ z,
                                            float* __restrict__ out)
{
    const int b = threadIdx.x;
    out[b] = z[b] - z[b + BB];
}

extern "C" void kernel_launch(void* const* d_in, const int* in_sizes, int n_in,
                              void* d_out, int out_size, void* d_ws, size_t ws_size,
                              hipStream_t stream) {
    const float* em    = (const float*)d_in[0];
    const int*   mask  = (const int*)d_in[1];
    const int*   tgt   = (const int*)d_in[2];
    const float* trans = (const float*)d_in[3];
    const float* start = (const float*)d_in[4];
    const int*   forb  = (const int*)d_in[5];

    const size_t need = (size_t)(2 * 2 * BB * KK + 4 * BB) * sizeof(float); // 132 KB
    if (ws_size >= need) {
        float* ef  = (float*)d_ws;                       // [128][128]
        float* db  = ef + 2 * BB * KK;                   // [128][128]
        float* Mfb = db + 2 * BB * KK;                   // [256]
        crf_fb_kernel<<<4 * BB, 128, 0, stream>>>(em, mask, tgt, trans, start,
                                                  forb, ef, db, Mfb);
        crf_combine_kernel<<<BB, 128, 0, stream>>>(ef, db, Mfb, (float*)d_out);
    } else {
        float* zbuf = (float*)d_ws;
        crf_chain_kernel<<<2 * BB, 512, 0, stream>>>(em, mask, tgt, trans, start,
                                                     forb, zbuf);
        crf_final_kernel<<<1, BB, 0, stream>>>(zbuf, (float*)d_out);
    }
}